// Round 3
// baseline (134.208 us; speedup 1.0000x reference)
//
#include <hip/hip_runtime.h>
#include <math.h>

// Sequential scan over T timesteps of independent per-synapse ODEs.
// Parallelism exists only across N, so maximize TLP: float2 per thread
// (N/2 threads -> 1024 workgroups -> 4 blocks/CU = 16 waves/CU) instead of
// float4 (512 wg -> 8 waves/CU, measured 21% occupancy / 2.4 TB/s).
// Output is write-once -> nontemporal stores keep inputs resident in LLC.
// pre_voltage and astro_mod are dead inputs (never read / overwritten).

namespace {

constexpr float TAU_GABA_A = 10.0f, TAU_GABA_B = 150.0f;
constexpr float TAU_D = 200.0f, TAU_ACH = 150.0f, TAU_NE = 100.0f, TAU_CA = 800.0f;
constexpr float ALPHA_D = 0.8f, BETA_ACH = 0.5f, GAMMA_NE = 0.3f;
constexpr float ALPHA_CA = 0.03f, BETA_ASTRO = 0.3f;
constexpr float TRACE_DECAY = 0.95f, BASE_LR = 0.01f;
constexpr float W_MIN = 0.001f, W_MAX = 1.0f, ELIG_TH = 0.01f;
constexpr float E_GABA = -70.0f;

// Native clang vector type: __builtin_nontemporal_store rejects HIP's
// float2 class but accepts ext_vector_type.
typedef float nfloat2 __attribute__((ext_vector_type(2)));

__device__ __forceinline__ float clampf(float x, float lo, float hi) {
  return fminf(fmaxf(x, lo), hi);
}

struct Decays {
  float ga, gb, d, ach, ne, ca;
};

__device__ __forceinline__ float step_one(
    float p, float q, float v, float r,
    float& w, float& gA, float& gN, float& gGa, float& gGb, float& tr,
    float& D, float& A, float& NEl, float& Ca, const Decays& dc) {
  const bool spk = p > 1e-3f;
  tr = clampf((p > 0.0f) ? (tr * TRACE_DECAY + 0.1f * p) : tr, 0.0f, 1.0f);
  gA = clampf(gA + (spk ? 0.5f * p : 0.0f), 0.0f, 2.0f);
  gN = clampf(gN + (spk ? 0.3f * p : 0.0f), 0.0f, 1.0f);
  gGa = clampf(gGa * dc.ga + (spk ? 0.2f * p : 0.0f), 0.0f, 1.0f);
  gGb = clampf(gGb * dc.gb + (spk ? 0.1f * p : 0.0f), 0.0f, 0.5f);
  D = D * dc.d + ((fabsf(r) > 0.01f) ? 0.5f * clampf(r, 0.0f, 2.0f) : 0.0f);
  A = A * dc.ach + ((tr > 0.1f) ? 0.2f * tr : 0.0f);
  NEl = NEl * dc.ne;
  Ca = clampf(Ca * dc.ca + ALPHA_CA * p * q, 0.0f, 2.0f);
  const float M = clampf(1.0f + BETA_ASTRO * Ca, 0.5f, 2.0f);
  const float neuromod = ALPHA_D * (D - 1.0f) + BETA_ACH * (A - 1.0f) +
                         GAMMA_NE * (NEl - 1.0f);
  const float dw = BASE_LR * tr * neuromod * M;
  w = clampf(w + ((tr > ELIG_TH) ? dw : 0.0f), W_MIN, W_MAX);
  const float mg = 1.0f / (1.0f + __expf(-0.062f * v) * (1.0f / 3.57f));
  const float i_exc = (gA + gN * mg) * (0.0f - v);
  const float i_inh = (gGa + gGb) * (E_GABA - v);
  return w * M * (i_exc + i_inh);
}

__device__ __forceinline__ Decays make_decays(float dt_ms) {
  Decays dc;
  dc.ga = __expf(-dt_ms / TAU_GABA_A);
  dc.gb = __expf(-dt_ms / TAU_GABA_B);
  dc.d = __expf(-dt_ms / TAU_D);
  dc.ach = __expf(-dt_ms / TAU_ACH);
  dc.ne = __expf(-dt_ms / TAU_NE);
  dc.ca = __expf(-dt_ms / TAU_CA);
  return dc;
}

__global__ __launch_bounds__(256) void synapse_vec2(
    const float2* __restrict__ pre, const float2* __restrict__ post,
    const float2* __restrict__ vpost, const float2* __restrict__ rew,
    const float2* __restrict__ w0, const float2* __restrict__ gA0,
    const float2* __restrict__ gN0, const float2* __restrict__ gGa0,
    const float2* __restrict__ gGb0, const float2* __restrict__ tr0,
    const float2* __restrict__ D0, const float2* __restrict__ A0,
    const float2* __restrict__ NE0, const float2* __restrict__ Ca0,
    const float* __restrict__ dtp, float2* __restrict__ out, int n2, int T) {
  const int idx = blockIdx.x * blockDim.x + threadIdx.x;
  if (idx >= n2) return;

  const Decays dc = make_decays(dtp[0] * 1000.0f);

  float2 wv = w0[idx], gAv = gA0[idx], gNv = gN0[idx];
  float2 gGav = gGa0[idx], gGbv = gGb0[idx], trv = tr0[idx];
  float2 Dv = D0[idx], Av = A0[idx], NEv = NE0[idx], Cav = Ca0[idx];

  // prefetch t=0
  float2 p = pre[idx], q = post[idx], v = vpost[idx], r = rew[idx];

  for (int t = 0; t < T; ++t) {
    const size_t on = (size_t)((t + 1 < T) ? t + 1 : t) * n2 + idx;
    const float2 pn = pre[on], qn = post[on], vn = vpost[on], rn = rew[on];

    nfloat2 I;
    I.x = step_one(p.x, q.x, v.x, r.x, wv.x, gAv.x, gNv.x, gGav.x, gGbv.x,
                   trv.x, Dv.x, Av.x, NEv.x, Cav.x, dc);
    I.y = step_one(p.y, q.y, v.y, r.y, wv.y, gAv.y, gNv.y, gGav.y, gGbv.y,
                   trv.y, Dv.y, Av.y, NEv.y, Cav.y, dc);
    __builtin_nontemporal_store(
        I, reinterpret_cast<nfloat2*>(&out[(size_t)t * n2 + idx]));

    p = pn; q = qn; v = vn; r = rn;
  }
}

// Scalar fallback for odd N.
__global__ __launch_bounds__(256) void synapse_scalar(
    const float* __restrict__ pre, const float* __restrict__ post,
    const float* __restrict__ vpost, const float* __restrict__ rew,
    const float* __restrict__ w0, const float* __restrict__ gA0,
    const float* __restrict__ gN0, const float* __restrict__ gGa0,
    const float* __restrict__ gGb0, const float* __restrict__ tr0,
    const float* __restrict__ D0, const float* __restrict__ A0,
    const float* __restrict__ NE0, const float* __restrict__ Ca0,
    const float* __restrict__ dtp, float* __restrict__ out, int N, int T) {
  const int i = blockIdx.x * blockDim.x + threadIdx.x;
  if (i >= N) return;
  const Decays dc = make_decays(dtp[0] * 1000.0f);
  float w = w0[i], gA = gA0[i], gN = gN0[i], gGa = gGa0[i], gGb = gGb0[i];
  float tr = tr0[i], D = D0[i], A = A0[i], NEl = NE0[i], Ca = Ca0[i];
  for (int t = 0; t < T; ++t) {
    const size_t o = (size_t)t * N + i;
    out[o] = step_one(pre[o], post[o], vpost[o], rew[o], w, gA, gN, gGa, gGb,
                      tr, D, A, NEl, Ca, dc);
  }
}

}  // namespace

extern "C" void kernel_launch(void* const* d_in, const int* in_sizes, int n_in,
                              void* d_out, int out_size, void* d_ws,
                              size_t ws_size, hipStream_t stream) {
  const float* pre = (const float*)d_in[0];
  const float* post = (const float*)d_in[1];
  // d_in[2] = pre_voltage: never read.
  const float* vpost = (const float*)d_in[3];
  const float* rew = (const float*)d_in[4];
  const float* w = (const float*)d_in[5];
  const float* gA = (const float*)d_in[6];
  const float* gN = (const float*)d_in[7];
  const float* gGa = (const float*)d_in[8];
  const float* gGb = (const float*)d_in[9];
  const float* tr = (const float*)d_in[10];
  const float* D = (const float*)d_in[11];
  const float* A = (const float*)d_in[12];
  const float* NE = (const float*)d_in[13];
  const float* Ca = (const float*)d_in[14];
  // d_in[15] = astro_mod: dead (overwritten before read).
  const float* dt = (const float*)d_in[16];

  const int N = in_sizes[5];
  const int T = in_sizes[0] / N;
  float* out = (float*)d_out;

  if ((N & 1) == 0) {
    const int n2 = N >> 1;
    dim3 block(256), grid((n2 + 255) / 256);
    hipLaunchKernelGGL(synapse_vec2, grid, block, 0, stream,
                       (const float2*)pre, (const float2*)post,
                       (const float2*)vpost, (const float2*)rew,
                       (const float2*)w, (const float2*)gA, (const float2*)gN,
                       (const float2*)gGa, (const float2*)gGb,
                       (const float2*)tr, (const float2*)D, (const float2*)A,
                       (const float2*)NE, (const float2*)Ca, dt, (float2*)out,
                       n2, T);
  } else {
    dim3 block(256), grid((N + 255) / 256);
    hipLaunchKernelGGL(synapse_scalar, grid, block, 0, stream, pre, post,
                       vpost, rew, w, gA, gN, gGa, gGb, tr, D, A, NE, Ca, dt,
                       out, N, T);
  }
}

// Round 4
// 132.268 us; speedup vs baseline: 1.0147x; 1.0147x over previous
//
#include <hip/hip_runtime.h>
#include <math.h>

// Sequential scan over T timesteps of independent per-synapse ODEs.
// R3 lesson: float2/thread left only ~3.4 waves/SIMD -> per-iteration
// load->use dependency (~900 cy HBM latency) not covered by ~820 cycles of
// co-resident VALU issue -> 2.7x dead time. Go scalar: 1 elem/thread =
// 2048 blocks = 8 blocks/CU = 32 waves/CU (occupancy cap), 8 waves/SIMD
// ~960 cy of issue per latency window + 1-step prefetch.
// pre_voltage and astro_mod are dead inputs. NT stores keep LLC for inputs.

namespace {

constexpr float TAU_GABA_A = 10.0f, TAU_GABA_B = 150.0f;
constexpr float TAU_D = 200.0f, TAU_ACH = 150.0f, TAU_NE = 100.0f, TAU_CA = 800.0f;
constexpr float ALPHA_D = 0.8f, BETA_ACH = 0.5f, GAMMA_NE = 0.3f;
constexpr float ALPHA_CA = 0.03f, BETA_ASTRO = 0.3f;
constexpr float TRACE_DECAY = 0.95f, BASE_LR = 0.01f;
constexpr float W_MIN = 0.001f, W_MAX = 1.0f, ELIG_TH = 0.01f;
constexpr float E_GABA = -70.0f;

__device__ __forceinline__ float clampf(float x, float lo, float hi) {
  return fminf(fmaxf(x, lo), hi);
}

struct Decays {
  float ga, gb, d, ach, ne, ca;
};

__device__ __forceinline__ float step_one(
    float p, float q, float v, float r,
    float& w, float& gA, float& gN, float& gGa, float& gGb, float& tr,
    float& D, float& A, float& NEl, float& Ca, const Decays& dc) {
  const bool spk = p > 1e-3f;
  tr = clampf((p > 0.0f) ? (tr * TRACE_DECAY + 0.1f * p) : tr, 0.0f, 1.0f);
  gA = clampf(gA + (spk ? 0.5f * p : 0.0f), 0.0f, 2.0f);
  gN = clampf(gN + (spk ? 0.3f * p : 0.0f), 0.0f, 1.0f);
  gGa = clampf(gGa * dc.ga + (spk ? 0.2f * p : 0.0f), 0.0f, 1.0f);
  gGb = clampf(gGb * dc.gb + (spk ? 0.1f * p : 0.0f), 0.0f, 0.5f);
  D = D * dc.d + ((fabsf(r) > 0.01f) ? 0.5f * clampf(r, 0.0f, 2.0f) : 0.0f);
  A = A * dc.ach + ((tr > 0.1f) ? 0.2f * tr : 0.0f);
  NEl = NEl * dc.ne;
  Ca = clampf(Ca * dc.ca + ALPHA_CA * p * q, 0.0f, 2.0f);
  const float M = clampf(1.0f + BETA_ASTRO * Ca, 0.5f, 2.0f);
  const float neuromod = ALPHA_D * (D - 1.0f) + BETA_ACH * (A - 1.0f) +
                         GAMMA_NE * (NEl - 1.0f);
  const float dw = BASE_LR * tr * neuromod * M;
  w = clampf(w + ((tr > ELIG_TH) ? dw : 0.0f), W_MIN, W_MAX);
  const float mg = 1.0f / (1.0f + __expf(-0.062f * v) * (1.0f / 3.57f));
  const float i_exc = (gA + gN * mg) * (0.0f - v);
  const float i_inh = (gGa + gGb) * (E_GABA - v);
  return w * M * (i_exc + i_inh);
}

__device__ __forceinline__ Decays make_decays(float dt_ms) {
  Decays dc;
  dc.ga = __expf(-dt_ms / TAU_GABA_A);
  dc.gb = __expf(-dt_ms / TAU_GABA_B);
  dc.d = __expf(-dt_ms / TAU_D);
  dc.ach = __expf(-dt_ms / TAU_ACH);
  dc.ne = __expf(-dt_ms / TAU_NE);
  dc.ca = __expf(-dt_ms / TAU_CA);
  return dc;
}

__global__ __launch_bounds__(256, 8) void synapse_scalar(
    const float* __restrict__ pre, const float* __restrict__ post,
    const float* __restrict__ vpost, const float* __restrict__ rew,
    const float* __restrict__ w0, const float* __restrict__ gA0,
    const float* __restrict__ gN0, const float* __restrict__ gGa0,
    const float* __restrict__ gGb0, const float* __restrict__ tr0,
    const float* __restrict__ D0, const float* __restrict__ A0,
    const float* __restrict__ NE0, const float* __restrict__ Ca0,
    const float* __restrict__ dtp, float* __restrict__ out, int N, int T) {
  const int i = blockIdx.x * blockDim.x + threadIdx.x;
  if (i >= N) return;

  const Decays dc = make_decays(dtp[0] * 1000.0f);

  float w = w0[i], gA = gA0[i], gN = gN0[i], gGa = gGa0[i], gGb = gGb0[i];
  float tr = tr0[i], D = D0[i], A = A0[i], NEl = NE0[i], Ca = Ca0[i];

  // prefetch t=0
  float p = pre[i], q = post[i], v = vpost[i], r = rew[i];

  for (int t = 0; t < T; ++t) {
    // issue next timestep's loads before this step's compute
    const size_t on = (size_t)((t + 1 < T) ? t + 1 : t) * N + i;
    const float pn = pre[on], qn = post[on], vn = vpost[on], rn = rew[on];

    const float I = step_one(p, q, v, r, w, gA, gN, gGa, gGb, tr, D, A, NEl,
                             Ca, dc);
    __builtin_nontemporal_store(I, &out[(size_t)t * N + i]);

    p = pn; q = qn; v = vn; r = rn;
  }
}

}  // namespace

extern "C" void kernel_launch(void* const* d_in, const int* in_sizes, int n_in,
                              void* d_out, int out_size, void* d_ws,
                              size_t ws_size, hipStream_t stream) {
  const float* pre = (const float*)d_in[0];
  const float* post = (const float*)d_in[1];
  // d_in[2] = pre_voltage: never read.
  const float* vpost = (const float*)d_in[3];
  const float* rew = (const float*)d_in[4];
  const float* w = (const float*)d_in[5];
  const float* gA = (const float*)d_in[6];
  const float* gN = (const float*)d_in[7];
  const float* gGa = (const float*)d_in[8];
  const float* gGb = (const float*)d_in[9];
  const float* tr = (const float*)d_in[10];
  const float* D = (const float*)d_in[11];
  const float* A = (const float*)d_in[12];
  const float* NE = (const float*)d_in[13];
  const float* Ca = (const float*)d_in[14];
  // d_in[15] = astro_mod: dead (overwritten before read).
  const float* dt = (const float*)d_in[16];

  const int N = in_sizes[5];
  const int T = in_sizes[0] / N;
  float* out = (float*)d_out;

  dim3 block(256), grid((N + 255) / 256);
  hipLaunchKernelGGL(synapse_scalar, grid, block, 0, stream, pre, post, vpost,
                     rew, w, gA, gN, gGa, gGb, tr, D, A, NE, Ca, dt, out, N,
                     T);
}

// Round 5
// 129.863 us; speedup vs baseline: 1.0335x; 1.0185x over previous
//
#include <hip/hip_runtime.h>
#include <math.h>

// Sequential scan over T timesteps of independent per-synapse ODEs.
// R4 lesson: dur_us invariant (~132us) across occupancy 21/42/80% -> not
// TLP-latency-bound. Demand traffic (671MB) / 132us = 5.1 TB/s, ~80% of the
// 6.3 TB/s pipe ceiling; VALUBusy*dur ~ 68us. Partial-overlap sum model fits.
// This round: cut VALU ~40% (shared spike gate, med3 clamps, v_rcp for the
// Mg divide, single v_exp, algebraic I) + depth-2 prefetch.
// pre_voltage and astro_mod are dead inputs. NT stores spare LLC for inputs.

namespace {

constexpr float TAU_D = 200.0f, TAU_ACH = 150.0f, TAU_NE = 100.0f;
constexpr float ALPHA_D = 0.8f, BETA_ACH = 0.5f, GAMMA_NE = 0.3f;
constexpr float ALPHA_CA = 0.03f, BETA_ASTRO = 0.3f;
constexpr float TRACE_DECAY = 0.95f, BASE_LR = 0.01f;
constexpr float W_MIN = 0.001f, W_MAX = 1.0f, ELIG_TH = 0.01f;

__device__ __forceinline__ float med3(float x, float lo, float hi) {
#if __has_builtin(__builtin_amdgcn_fmed3f)
  return __builtin_amdgcn_fmed3f(x, lo, hi);
#else
  return fminf(fmaxf(x, lo), hi);
#endif
}

__device__ __forceinline__ float fast_rcp(float x) {
#if __has_builtin(__builtin_amdgcn_rcpf)
  return __builtin_amdgcn_rcpf(x);  // v_rcp_f32, ~1 ulp
#else
  return 1.0f / x;
#endif
}

__device__ __forceinline__ float fast_exp2(float x) {
#if __has_builtin(__builtin_amdgcn_exp2f)
  return __builtin_amdgcn_exp2f(x);  // v_exp_f32
#else
  return exp2f(x);
#endif
}

struct Decays {
  float ga, gb, d, ach, ne, ca;
};

__device__ __forceinline__ Decays make_decays(float dt_ms) {
  // exp(-dt/tau) = exp2(-dt * log2(e)/tau); constants folded at compile time.
  constexpr float L2E = 1.4426950408889634f;
  Decays dc;
  dc.ga = fast_exp2(dt_ms * (-L2E / 10.0f));
  dc.gb = fast_exp2(dt_ms * (-L2E / 150.0f));
  dc.d = fast_exp2(dt_ms * (-L2E / TAU_D));
  dc.ach = fast_exp2(dt_ms * (-L2E / TAU_ACH));
  dc.ne = fast_exp2(dt_ms * (-L2E / TAU_NE));
  dc.ca = fast_exp2(dt_ms * (-L2E / 800.0f));
  return dc;
}

__device__ __forceinline__ float step_one(
    float p, float q, float v, float r,
    float& w, float& gA, float& gN, float& gGa, float& gGb, float& tr,
    float& D, float& A, float& NEl, float& Ca, const Decays& dc) {
  // shared spike-gated p (p>1e-3 gate for all four conductance increments)
  const float ps = (p > 1e-3f) ? p : 0.0f;
  // eligibility trace (gate is p>0, distinct from spike gate)
  tr = (p > 0.0f) ? fmaf(tr, TRACE_DECAY, 0.1f * p) : tr;
  tr = med3(tr, 0.0f, 1.0f);
  // conductances
  gA = med3(fmaf(0.5f, ps, gA), 0.0f, 2.0f);
  gN = med3(fmaf(0.3f, ps, gN), 0.0f, 1.0f);
  gGa = med3(fmaf(gGa, dc.ga, 0.2f * ps), 0.0f, 1.0f);
  gGb = med3(fmaf(gGb, dc.gb, 0.1f * ps), 0.0f, 0.5f);
  // neuromodulators
  const float rc = (fabsf(r) > 0.01f) ? 0.5f * med3(r, 0.0f, 2.0f) : 0.0f;
  D = fmaf(D, dc.d, rc);
  const float ac = (tr > 0.1f) ? 0.2f * tr : 0.0f;
  A = fmaf(A, dc.ach, ac);
  NEl *= dc.ne;
  // astrocyte
  Ca = med3(fmaf(Ca, dc.ca, (ALPHA_CA * p) * q), 0.0f, 2.0f);
  const float M = med3(fmaf(BETA_ASTRO, Ca, 1.0f), 0.5f, 2.0f);
  // three-factor weight update; 0.8(D-1)+0.5(A-1)+0.3(NE-1) folded
  const float neuromod =
      fmaf(ALPHA_D, D, fmaf(BETA_ACH, A, fmaf(GAMMA_NE, NEl, -1.6f)));
  const float dwv = (BASE_LR * tr) * (neuromod * M);
  w = med3(w + ((tr > ELIG_TH) ? dwv : 0.0f), W_MIN, W_MAX);
  // NMDA Mg block: 1/(1 + exp(-0.062 v)/3.57); exp via single v_exp_f32
  const float ex = fast_exp2(-0.08944709253511573f * v);  // -0.062*log2(e)
  const float mg = fast_rcp(fmaf(ex, 0.28011204481792717f, 1.0f));
  // I = w*M*(eA*(0-v) + (gGa+gGb)*(-70-v)) = -(w*M)*(eA*v + gI*(v+70))
  const float eA = fmaf(gN, mg, gA);
  const float gI = gGa + gGb;
  const float s = fmaf(gI, v + 70.0f, eA * v);
  return -(w * M) * s;
}

__global__ __launch_bounds__(256, 8) void synapse_scalar(
    const float* __restrict__ pre, const float* __restrict__ post,
    const float* __restrict__ vpost, const float* __restrict__ rew,
    const float* __restrict__ w0, const float* __restrict__ gA0,
    const float* __restrict__ gN0, const float* __restrict__ gGa0,
    const float* __restrict__ gGb0, const float* __restrict__ tr0,
    const float* __restrict__ D0, const float* __restrict__ A0,
    const float* __restrict__ NE0, const float* __restrict__ Ca0,
    const float* __restrict__ dtp, float* __restrict__ out, int N, int T) {
  const int i = blockIdx.x * blockDim.x + threadIdx.x;
  if (i >= N) return;

  const Decays dc = make_decays(dtp[0] * 1000.0f);

  float w = w0[i], gA = gA0[i], gN = gN0[i], gGa = gGa0[i], gGb = gGb0[i];
  float tr = tr0[i], D = D0[i], A = A0[i], NEl = NE0[i], Ca = Ca0[i];

  // depth-2 prefetch (T = 64 >= 2)
  size_t off = (size_t)i;
  float p0 = pre[off], q0 = post[off], v0 = vpost[off], r0 = rew[off];
  const size_t offb = off + (size_t)N;
  float p1 = pre[offb], q1 = post[offb], v1 = vpost[offb], r1 = rew[offb];

  int t = 0;
  for (; t < T - 2; ++t) {
    const size_t offn = off + 2 * (size_t)N;
    const float pn = pre[offn], qn = post[offn], vn = vpost[offn],
                rn = rew[offn];

    const float I =
        step_one(p0, q0, v0, r0, w, gA, gN, gGa, gGb, tr, D, A, NEl, Ca, dc);
    __builtin_nontemporal_store(I, &out[off]);

    p0 = p1; q0 = q1; v0 = v1; r0 = r1;
    p1 = pn; q1 = qn; v1 = vn; r1 = rn;
    off += (size_t)N;
  }
  for (; t < T; ++t) {  // tail: no prefetch
    const float I =
        step_one(p0, q0, v0, r0, w, gA, gN, gGa, gGb, tr, D, A, NEl, Ca, dc);
    __builtin_nontemporal_store(I, &out[off]);
    p0 = p1; q0 = q1; v0 = v1; r0 = r1;
    off += (size_t)N;
  }
}

}  // namespace

extern "C" void kernel_launch(void* const* d_in, const int* in_sizes, int n_in,
                              void* d_out, int out_size, void* d_ws,
                              size_t ws_size, hipStream_t stream) {
  const float* pre = (const float*)d_in[0];
  const float* post = (const float*)d_in[1];
  // d_in[2] = pre_voltage: never read.
  const float* vpost = (const float*)d_in[3];
  const float* rew = (const float*)d_in[4];
  const float* w = (const float*)d_in[5];
  const float* gA = (const float*)d_in[6];
  const float* gN = (const float*)d_in[7];
  const float* gGa = (const float*)d_in[8];
  const float* gGb = (const float*)d_in[9];
  const float* tr = (const float*)d_in[10];
  const float* D = (const float*)d_in[11];
  const float* A = (const float*)d_in[12];
  const float* NE = (const float*)d_in[13];
  const float* Ca = (const float*)d_in[14];
  // d_in[15] = astro_mod: dead (overwritten before read).
  const float* dt = (const float*)d_in[16];

  const int N = in_sizes[5];
  const int T = in_sizes[0] / N;
  float* out = (float*)d_out;

  dim3 block(256), grid((N + 255) / 256);
  hipLaunchKernelGGL(synapse_scalar, grid, block, 0, stream, pre, post, vpost,
                     rew, w, gA, gN, gGa, gGb, tr, D, A, NE, Ca, dt, out, N,
                     T);
}